// Round 1
// baseline (746.412 us; speedup 1.0000x reference)
//
#include <hip/hip_runtime.h>

#define T_LEN 1024
#define M_DIM 128
#define B_NUM 64

// One block per batch. 512 threads: j = tid&127 (output state), c = tid>>7 (i-chunk).
// Exp-space recurrence: u[i] = exp(S[i] - C); step = f32 matvec with W = exp(A_trans),
// renormalize by running max Z (division folded into next matvec), C += log(Z).
__global__ __launch_bounds__(512, 1) void crf_fwd(
    const float* __restrict__ P, const float* __restrict__ A,
    const int* __restrict__ Y, const int* __restrict__ L,
    float* __restrict__ out)
{
  const int b   = blockIdx.x;
  const int tid = threadIdx.x;
  const int j   = tid & 127;
  const int c   = tid >> 7;   // 0..3
  const int wid = tid >> 6;   // wave id 0..7

  __shared__ __align__(16) float u_lds[128];   // unnormalized exp-state
  __shared__ float partial[512];               // 4 partial matvec sums per j
  __shared__ float P_row[128];                 // P[b,t,:] for the sY chain
  __shared__ float red[8];                     // [0,1]=wave Zmax, [2,3]=wave sums, [6,7]=init max
  __shared__ int   Y_lds[T_LEN];

  // Stage Y[b,:] once (4 KB).
  for (int idx = tid; idx < T_LEN; idx += 512) Y_lds[idx] = Y[b * T_LEN + idx];

  // W in registers: w[k] = exp(A_trans[c*32+k][j]). Coalesced loads (lanes = consecutive j).
  float w[32];
  #pragma unroll
  for (int k = 0; k < 32; ++k)
    w[k] = __expf(A[(c * 32 + k) * M_DIM + j]);

  const int Lb = L[b];
  const float* Pb = P + (size_t)b * T_LEN * M_DIM;

  // ---- t = 0 ----
  float s0 = 0.f, p_cur = 0.f;
  if (c == 0) {
    p_cur = Pb[j];                       // P[b,0,j]
    s0 = p_cur + A[128 * M_DIM + j];     // + A_start[j]
    float mm = s0;
    #pragma unroll
    for (int d = 1; d < 64; d <<= 1) mm = fmaxf(mm, __shfl_xor(mm, d));
    if ((tid & 63) == 0) red[6 + wid] = mm;
  }
  __syncthreads();   // Y_lds + red[6,7] ready

  const int y0 = Y_lds[0];
  float sY = Pb[y0] + A[128 * M_DIM + y0];   // uniform broadcast loads
  float C = fmaxf(red[6], red[7]);           // m0
  if (c == 0) {
    float un = __expf(s0 - C);
    u_lds[j] = un;
    float zm = un, zs = un;
    #pragma unroll
    for (int d = 1; d < 64; d <<= 1) { zm = fmaxf(zm, __shfl_xor(zm, d)); zs += __shfl_xor(zs, d); }
    if ((tid & 63) == 0) { red[wid] = zm; red[2 + wid] = zs; }
  }
  __syncthreads();

  if (Lb == 1) {
    if (tid == 0) out[b] = __logf(red[2] + red[3]) + C - sY;
    return;
  }

  if (c == 0) p_cur = Pb[M_DIM + j];   // prefetch row t=1
  int y_prev = y0;

  for (int t = 1;; ++t) {
    // ---- Phase A: matvec on u (reads u_lds, red from prev step) ----
    const float Zprev = fmaxf(red[0], red[1]);
    const float invZ  = __builtin_amdgcn_rcpf(Zprev);
    const float4* u4 = (const float4*)u_lds;
    float a0 = 0.f, a1 = 0.f, a2 = 0.f, a3 = 0.f;
    #pragma unroll
    for (int k4 = 0; k4 < 8; ++k4) {
      float4 uu = u4[c * 8 + k4];       // uniform per wave -> broadcast ds_read_b128
      a0 = fmaf(uu.x, w[k4 * 4 + 0], a0);
      a1 = fmaf(uu.y, w[k4 * 4 + 1], a1);
      a2 = fmaf(uu.z, w[k4 * 4 + 2], a2);
      a3 = fmaf(uu.w, w[k4 * 4 + 3], a3);
    }
    partial[tid] = (a0 + a1) + (a2 + a3);

    float p_next = 0.f;
    if (c == 0) {
      P_row[j] = p_cur;                               // row t for the sY chain
      int tn = (t + 1 < T_LEN) ? t + 1 : T_LEN - 1;   // prefetch row t+1 (clamped)
      p_next = Pb[tn * M_DIM + j];
    }
    const int   y_t = Y_lds[t];
    const float a_y = A[y_prev * M_DIM + y_t];        // uniform broadcast, issued early
    __syncthreads();   // bar1: partial/P_row visible

    // ---- Phase B ----
    C  += __logf(Zprev);            // C_t = C_{t-1} + log Z_{t-1}
    sY += P_row[y_t] + a_y;
    y_prev = y_t;
    const bool last = (t == Lb - 1);

    if (c == 0) {
      float v  = ((partial[j] + partial[j + 128]) +
                  (partial[j + 256] + partial[j + 384])) * invZ;
      float un = v * __expf(p_cur);   // p_cur = P[b,t,j]
      u_lds[j] = un;
      float zm = un;
      #pragma unroll
      for (int d = 1; d < 64; d <<= 1) zm = fmaxf(zm, __shfl_xor(zm, d));
      if ((tid & 63) == 0) red[wid] = zm;
      if (last) {
        float zs = un;
        #pragma unroll
        for (int d = 1; d < 64; d <<= 1) zs += __shfl_xor(zs, d);
        if ((tid & 63) == 0) red[2 + wid] = zs;
      }
      p_cur = p_next;
    }
    __syncthreads();   // bar2: u_lds/red visible for next step

    if (last) {
      if (tid == 0) out[b] = __logf(red[2] + red[3]) + C - sY;
      return;
    }
  }
}

extern "C" void kernel_launch(void* const* d_in, const int* in_sizes, int n_in,
                              void* d_out, int out_size, void* d_ws, size_t ws_size,
                              hipStream_t stream) {
  const float* P = (const float*)d_in[0];
  const float* A = (const float*)d_in[1];
  const int*   Y = (const int*)d_in[2];
  const int*   L = (const int*)d_in[3];
  float* o = (float*)d_out;
  hipLaunchKernelGGL(crf_fwd, dim3(B_NUM), dim3(512), 0, stream, P, A, Y, L, o);
}